// Round 2
// baseline (46.952 us; speedup 1.0000x reference)
//
#include <hip/hip_runtime.h>

#define BLOCK 256
#define MAX_LDS_CENTERS 4096

typedef float f32x4 __attribute__((ext_vector_type(4)));

__global__ __launch_bounds__(BLOCK) void sinusoidal_kernel(
    const float* __restrict__ t,
    const float* __restrict__ weights,
    const float* __restrict__ c_ptr,
    const int*   __restrict__ nc_ptr,
    float*       __restrict__ out,
    int n4, int n)
{
    __shared__ float ws[MAX_LDS_CENTERS];

    const int   nc    = nc_ptr[0];
    const float c     = c_ptr[0];
    const float inv_c = 1.0f / c;
    const float PI_F  = 3.14159265358979f;

    const bool use_lds = (nc <= MAX_LDS_CENTERS);
    if (use_lds) {
        for (int i = threadIdx.x; i < nc; i += BLOCK) ws[i] = weights[i];
    }
    __syncthreads();

    const bool pow2 = ((nc & (nc - 1)) == 0);
    const int  mask = nc - 1;
    const float* __restrict__ wtab = use_lds ? ws : weights;

    const int tid    = blockIdx.x * BLOCK + threadIdx.x;
    const int stride = gridDim.x * BLOCK;

    const f32x4* __restrict__ t4 = reinterpret_cast<const f32x4*>(t);
    f32x4*       __restrict__ o4 = reinterpret_cast<f32x4*>(out);

    for (int i = tid; i < n4; i += stride) {
        f32x4 tv = t4[i];
        float os[4];
        #pragma unroll
        for (int j = 0; j < 4; ++j) {
            float x  = tv[j] * inv_c;
            float bf = floorf(x);
            float fr = x - bf;                 // in [0,1)
            float s  = __sinf(PI_F * fr);      // small-arg fast sin
            int bin  = (int)bf;                // t >= 0 so floor==trunc ok
            s = (bin & 1) ? -s : s;            // (-1)^bin
            int widx = bin >> 1;
            widx = pow2 ? (widx & mask) : (widx % nc);
            os[j] = wtab[widx] * s;
        }
        f32x4 ov;
        ov[0] = os[0]; ov[1] = os[1]; ov[2] = os[2]; ov[3] = os[3];
        __builtin_nontemporal_store(ov, &o4[i]);   // don't allocate out in L2/L3
    }

    // scalar tail (n not divisible by 4)
    int tail_start = n4 * 4;
    for (int i = tail_start + tid; i < n; i += stride) {
        float x  = t[i] * inv_c;
        float bf = floorf(x);
        float fr = x - bf;
        float s  = __sinf(PI_F * fr);
        int bin  = (int)bf;
        s = (bin & 1) ? -s : s;
        int widx = bin >> 1;
        widx = pow2 ? (widx & mask) : (widx % nc);
        __builtin_nontemporal_store(wtab[widx] * s, &out[i]);
    }
}

extern "C" void kernel_launch(void* const* d_in, const int* in_sizes, int n_in,
                              void* d_out, int out_size, void* d_ws, size_t ws_size,
                              hipStream_t stream) {
    const float* t  = (const float*)d_in[0];
    const float* w  = (const float*)d_in[1];
    const float* c  = (const float*)d_in[2];
    const int*   nc = (const int*)d_in[3];
    float* out = (float*)d_out;

    int n  = in_sizes[0];
    int n4 = n / 4;

    int grid = (n4 + BLOCK - 1) / BLOCK;
    if (grid > 2048) grid = 2048;
    if (grid < 1) grid = 1;

    sinusoidal_kernel<<<grid, BLOCK, 0, stream>>>(t, w, c, nc, out, n4, n);
}

// Round 3
// 46.422 us; speedup vs baseline: 1.0114x; 1.0114x over previous
//
#include <hip/hip_runtime.h>

#define BLOCK 256
#define GRID 2048
#define UNROLL 4
#define MAX_LDS_CENTERS 4096

typedef float f32x4 __attribute__((ext_vector_type(4)));

__global__ __launch_bounds__(BLOCK) void sinusoidal_kernel(
    const float* __restrict__ t,
    const float* __restrict__ weights,
    const float* __restrict__ c_ptr,
    const int*   __restrict__ nc_ptr,
    float*       __restrict__ out,
    int n4, int n)
{
    __shared__ float ws[MAX_LDS_CENTERS];

    const int   nc = nc_ptr[0];
    // sin(pi * t/c) = sin(2*pi * fract(t/(2c))) ; idx = floor(t/(2c)) % nc
    const float k  = 0.5f / c_ptr[0];

    const bool use_lds = (nc <= MAX_LDS_CENTERS);
    if (use_lds) {
        for (int i = threadIdx.x; i < nc; i += BLOCK) ws[i] = weights[i];
    }
    __syncthreads();

    const bool pow2 = ((nc & (nc - 1)) == 0);
    const int  mask = nc - 1;
    const float* __restrict__ wtab = use_lds ? ws : weights;

    const int tid    = blockIdx.x * BLOCK + threadIdx.x;
    const int stride = gridDim.x * BLOCK;

    const f32x4* __restrict__ t4 = reinterpret_cast<const f32x4*>(t);
    f32x4*       __restrict__ o4 = reinterpret_cast<f32x4*>(out);

    int i = tid;
    // main: UNROLL independent float4 loads in flight per iteration
    for (; i + (UNROLL - 1) * stride < n4; i += UNROLL * stride) {
        f32x4 tv[UNROLL];
        #pragma unroll
        for (int u = 0; u < UNROLL; ++u) tv[u] = t4[i + u * stride];

        #pragma unroll
        for (int u = 0; u < UNROLL; ++u) {
            f32x4 ov;
            #pragma unroll
            for (int j = 0; j < 4; ++j) {
                float r  = tv[u][j] * k;                 // revolutions/2pi
                float rf = floorf(r);
                float fr = r - rf;                       // [0,1)
                float s  = __builtin_amdgcn_sinf(fr);    // sin(2*pi*fr) = sin(pi*x)
                int widx = (int)rf;                      // floor(bin/2)
                widx = pow2 ? (widx & mask) : (widx % nc);
                ov[j] = wtab[widx] * s;
            }
            __builtin_nontemporal_store(ov, &o4[i + u * stride]);
        }
    }
    // leftover float4s
    for (; i < n4; i += stride) {
        f32x4 tv = t4[i];
        f32x4 ov;
        #pragma unroll
        for (int j = 0; j < 4; ++j) {
            float r  = tv[j] * k;
            float rf = floorf(r);
            float fr = r - rf;
            float s  = __builtin_amdgcn_sinf(fr);
            int widx = (int)rf;
            widx = pow2 ? (widx & mask) : (widx % nc);
            ov[j] = wtab[widx] * s;
        }
        __builtin_nontemporal_store(ov, &o4[i]);
    }
    // scalar tail (n not divisible by 4)
    int tail_start = n4 * 4;
    for (int idx2 = tail_start + tid; idx2 < n; idx2 += stride) {
        float r  = t[idx2] * k;
        float rf = floorf(r);
        float fr = r - rf;
        float s  = __builtin_amdgcn_sinf(fr);
        int widx = (int)rf;
        widx = pow2 ? (widx & mask) : (widx % nc);
        __builtin_nontemporal_store(wtab[widx] * s, &out[idx2]);
    }
}

extern "C" void kernel_launch(void* const* d_in, const int* in_sizes, int n_in,
                              void* d_out, int out_size, void* d_ws, size_t ws_size,
                              hipStream_t stream) {
    const float* t  = (const float*)d_in[0];
    const float* w  = (const float*)d_in[1];
    const float* c  = (const float*)d_in[2];
    const int*   nc = (const int*)d_in[3];
    float* out = (float*)d_out;

    int n  = in_sizes[0];
    int n4 = n / 4;

    int grid = (n4 + BLOCK - 1) / BLOCK;
    if (grid > GRID) grid = GRID;
    if (grid < 1) grid = 1;

    sinusoidal_kernel<<<grid, BLOCK, 0, stream>>>(t, w, c, nc, out, n4, n);
}

// Round 4
// 45.410 us; speedup vs baseline: 1.0339x; 1.0223x over previous
//
#include <hip/hip_runtime.h>

#define BLOCK 256
#define UNROLL 8
#define TILE (BLOCK * UNROLL)   // float4s per block-iteration (2048 = 32 KB)
#define MAXGRID 4096
#define MAX_LDS_CENTERS 4096

typedef float f32x4 __attribute__((ext_vector_type(4)));

__global__ __launch_bounds__(BLOCK) void sinusoidal_kernel(
    const float* __restrict__ t,
    const float* __restrict__ weights,
    const float* __restrict__ c_ptr,
    const int*   __restrict__ nc_ptr,
    float*       __restrict__ out,
    int n4, int n, int ntiles)
{
    __shared__ __align__(16) float ws[MAX_LDS_CENTERS];

    const int   nc = nc_ptr[0];
    // sin(pi * t/c) = sin(2*pi * fract(t/(2c))) ; idx = floor(t/(2c)) % nc
    const float k  = 0.5f / c_ptr[0];

    const bool use_lds = (nc <= MAX_LDS_CENTERS);
    if (use_lds) {
        // stage with float4 loads: nc/4 float4s spread across BLOCK threads
        const f32x4* __restrict__ w4 = reinterpret_cast<const f32x4*>(weights);
        f32x4* ws4 = reinterpret_cast<f32x4*>(ws);
        for (int i = threadIdx.x; i < (nc >> 2); i += BLOCK) ws4[i] = w4[i];
    }
    __syncthreads();

    const bool pow2 = ((nc & (nc - 1)) == 0);
    const int  mask = nc - 1;
    const float* __restrict__ wtab = use_lds ? ws : weights;

    const f32x4* __restrict__ t4 = reinterpret_cast<const f32x4*>(t);
    f32x4*       __restrict__ o4 = reinterpret_cast<f32x4*>(out);

    // main: each block-iteration consumes one CONTIGUOUS 32 KB tile
    for (int tile = blockIdx.x; tile < ntiles; tile += gridDim.x) {
        const int base = tile * TILE + (int)threadIdx.x;

        f32x4 tv[UNROLL];
        #pragma unroll
        for (int u = 0; u < UNROLL; ++u) tv[u] = t4[base + u * BLOCK];

        #pragma unroll
        for (int u = 0; u < UNROLL; ++u) {
            f32x4 ov;
            #pragma unroll
            for (int j = 0; j < 4; ++j) {
                float r  = tv[u][j] * k;                 // half-periods/2
                float rf = floorf(r);
                float fr = r - rf;                       // [0,1)
                float s  = __builtin_amdgcn_sinf(fr);    // sin(2*pi*fr) = sin(pi*x)
                int widx = (int)rf;                      // (bin>>1)
                widx = pow2 ? (widx & mask) : (widx % nc);
                ov[j] = wtab[widx] * s;
            }
            __builtin_nontemporal_store(ov, &o4[base + u * BLOCK]);
        }
    }

    // leftover float4s beyond the last full tile
    const int done4  = ntiles * TILE;
    const int tid    = blockIdx.x * BLOCK + threadIdx.x;
    const int stride = gridDim.x * BLOCK;
    for (int i = done4 + tid; i < n4; i += stride) {
        f32x4 tv = t4[i];
        f32x4 ov;
        #pragma unroll
        for (int j = 0; j < 4; ++j) {
            float r  = tv[j] * k;
            float rf = floorf(r);
            float fr = r - rf;
            float s  = __builtin_amdgcn_sinf(fr);
            int widx = (int)rf;
            widx = pow2 ? (widx & mask) : (widx % nc);
            ov[j] = wtab[widx] * s;
        }
        __builtin_nontemporal_store(ov, &o4[i]);
    }

    // scalar tail (n not divisible by 4)
    for (int i = n4 * 4 + tid; i < n; i += stride) {
        float r  = t[i] * k;
        float rf = floorf(r);
        float fr = r - rf;
        float s  = __builtin_amdgcn_sinf(fr);
        int widx = (int)rf;
        widx = pow2 ? (widx & mask) : (widx % nc);
        __builtin_nontemporal_store(wtab[widx] * s, &out[i]);
    }
}

extern "C" void kernel_launch(void* const* d_in, const int* in_sizes, int n_in,
                              void* d_out, int out_size, void* d_ws, size_t ws_size,
                              hipStream_t stream) {
    const float* t  = (const float*)d_in[0];
    const float* w  = (const float*)d_in[1];
    const float* c  = (const float*)d_in[2];
    const int*   nc = (const int*)d_in[3];
    float* out = (float*)d_out;

    int n      = in_sizes[0];
    int n4     = n / 4;
    int ntiles = n4 / TILE;

    int grid = ntiles;
    if (grid > MAXGRID) grid = MAXGRID;
    if (grid < 1) grid = 1;

    sinusoidal_kernel<<<grid, BLOCK, 0, stream>>>(t, w, c, nc, out, n4, n, ntiles);
}